// Round 3
// baseline (285.476 us; speedup 1.0000x reference)
//
#include <hip/hip_runtime.h>
#include <hip/hip_bf16.h>
#include <math.h>

// Problem constants (fixed by setup_inputs)
#define G_NUM   64
#define N_NODES 512
#define K_NN    16
#define TOTAL   (G_NUM * N_NODES)   // 32768
#define E_TOTAL (TOTAL * K_NN)      // 524288
#define D0 4
#define D1 64
#define D2 128
#define D3 256

typedef _Float16 half8  __attribute__((ext_vector_type(8)));
typedef _Float16 half4t __attribute__((ext_vector_type(4)));
typedef _Float16 half2t __attribute__((ext_vector_type(2)));
typedef float    f32x4  __attribute__((ext_vector_type(4)));

// ---------------------------------------------------------------------------
// Kernel 0: prepack W2 [128][64] and W3 [256][128] to f16 in ws (row-major).
// ---------------------------------------------------------------------------
__global__ __launch_bounds__(256) void prepack_kernel(const float* __restrict__ W2,
                                                      const float* __restrict__ W3,
                                                      _Float16* __restrict__ wsh) {
    const int i = blockIdx.x * 256 + threadIdx.x;
    if (i < D2 * D1) wsh[i] = (_Float16)W2[i];                     // 8192
    const int j = i - D2 * D1;
    if (j >= 0 && j < D3 * D2) wsh[D2 * D1 + j] = (_Float16)W3[j]; // 32768
}

// ---------------------------------------------------------------------------
// Kernel 1: per-graph Euclidean KNN (k=16, no self-loop, ties -> lower index).
// ---------------------------------------------------------------------------
__global__ __launch_bounds__(128) void knn_kernel(const float* __restrict__ loc,
                                                  float* __restrict__ out_ei) {
    __shared__ float posx[N_NODES];
    __shared__ float posy[N_NODES];
    const int g  = blockIdx.x;
    const int t  = threadIdx.x;
    const int n  = blockIdx.y * 128 + t;

    for (int i = t; i < N_NODES; i += 128) {
        const float* row = loc + (size_t)(g * N_NODES + i) * 10;
        posx[i] = row[6];
        posy[i] = row[7];
    }
    __syncthreads();

    const float px = posx[n];
    const float py = posy[n];

    float dist[K_NN];
    int   idx[K_NN];
#pragma unroll
    for (int j = 0; j < K_NN; ++j) { dist[j] = INFINITY; idx[j] = 0; }

    for (int c = 0; c < N_NODES; ++c) {
        if (c == n) continue;
        const float dx = posx[c] - px;
        const float dy = posy[c] - py;
        const float d  = dx * dx + dy * dy;
        if (d < dist[K_NN - 1]) {
            dist[K_NN - 1] = d;
            idx[K_NN - 1]  = c;
#pragma unroll
            for (int j = K_NN - 1; j > 0; --j) {
                if (dist[j] < dist[j - 1]) {
                    float td = dist[j]; dist[j] = dist[j - 1]; dist[j - 1] = td;
                    int   ti = idx[j];  idx[j]  = idx[j - 1];  idx[j - 1]  = ti;
                }
            }
        }
    }

    const int node  = g * N_NODES + n;
    const size_t eb = (size_t)node * K_NN;
#pragma unroll
    for (int j = 0; j < K_NN; ++j) {
        const int s = g * N_NODES + idx[j];
        out_ei[eb + j]            = (float)s;
        out_ei[E_TOTAL + eb + j]  = (float)node;
    }
}

// ---------------------------------------------------------------------------
// Kernel 2: fused features + layer1 (f32 VALU) + layers 2,3 (f16 MFMA).
// Operand-swapped MFMA: D[row=channel][col=edge] -> each lane owns 4
// consecutive output channels of one edge -> float4 nontemporal stores.
// Block = 256 threads (4 waves), tile = 64 edges.
// ---------------------------------------------------------------------------
__global__ __launch_bounds__(256) void mlp_kernel(const float* __restrict__ loc,
                                                  const float* __restrict__ ei_src,
                                                  const float* __restrict__ W1,
                                                  const float* __restrict__ b1,
                                                  const float* __restrict__ b2,
                                                  const float* __restrict__ b3,
                                                  const _Float16* __restrict__ wsh,
                                                  float* __restrict__ out) {
    __shared__ float     feat[64][4];
    __shared__ _Float16  h1s[64][D1 + 8];   // stride 72 f16 (2-way LDS aliasing = free)
    __shared__ _Float16  h2s[64][D2 + 8];   // stride 136 f16

    const int t = threadIdx.x;
    const int w = t >> 6;          // wave 0..3
    const int l = t & 63;          // lane
    const int lr = l & 15;
    const int lq = l >> 4;
    const size_t tile_base = (size_t)blockIdx.x * 64;

    const _Float16* w2h = wsh;                 // [128][64]
    const _Float16* w3h = wsh + D2 * D1;       // [256][128]

    // ---- Phase 0: raw edge features (threads 0..63) ----
    if (t < 64) {
        const size_t e  = tile_base + t;
        const int src   = (int)ei_src[e];
        const int tgt   = (int)(e >> 4);
        const float* sr = loc + (size_t)src * 10;
        const float* tr = loc + (size_t)tgt * 10;
        feat[t][0] = (sr[6] - tr[6]) / sr[8];
        feat[t][1] = (sr[7] - tr[7]) / sr[9];
        feat[t][2] = logf(sr[4] / tr[4]);
        feat[t][3] = logf(sr[5] / tr[5]);
    }
    __syncthreads();

    // ---- Layer 1 (f32): edge = l, wave w computes channels w*16..w*16+15 ----
    {
        const float f0 = feat[l][0], f1 = feat[l][1], f2 = feat[l][2], f3 = feat[l][3];
#pragma unroll
        for (int u = 0; u < 8; ++u) {
            const int o0 = w * 16 + 2 * u;
            float a0 = b1[o0]     + f0 * W1[o0 * 4]     + f1 * W1[o0 * 4 + 1]
                                  + f2 * W1[o0 * 4 + 2] + f3 * W1[o0 * 4 + 3];
            float a1 = b1[o0 + 1] + f0 * W1[o0 * 4 + 4] + f1 * W1[o0 * 4 + 5]
                                  + f2 * W1[o0 * 4 + 6] + f3 * W1[o0 * 4 + 7];
            half2t p;
            p[0] = (_Float16)fmaxf(a0, 0.0f);
            p[1] = (_Float16)fmaxf(a1, 0.0f);
            *(half2t*)&h1s[l][o0] = p;
        }
    }
    __syncthreads();

    // ---- Layer 2 (MFMA, swapped): wave w -> channels [w*32, w*32+32) ----
    {
        f32x4 acc[2][4];   // [ch-tile][edge-tile]
#pragma unroll
        for (int nn = 0; nn < 2; ++nn) {
            const f32x4 bc = *(const f32x4*)&b2[w * 32 + nn * 16 + lq * 4];
#pragma unroll
            for (int m = 0; m < 4; ++m) acc[nn][m] = bc;
        }
#pragma unroll
        for (int kt = 0; kt < 2; ++kt) {
            half8 wf[2];
#pragma unroll
            for (int nn = 0; nn < 2; ++nn)
                wf[nn] = *(const half8*)(w2h + (w * 32 + nn * 16 + lr) * D1 + kt * 32 + lq * 8);
#pragma unroll
            for (int m = 0; m < 4; ++m) {
                const half8 hf = *(const half8*)&h1s[m * 16 + lr][kt * 32 + lq * 8];
#pragma unroll
                for (int nn = 0; nn < 2; ++nn)
                    acc[nn][m] = __builtin_amdgcn_mfma_f32_16x16x32_f16(wf[nn], hf, acc[nn][m], 0, 0, 0);
            }
        }
        // h2 write: lane owns edge (m*16+lr), 4 consecutive channels -> ds_write_b64
#pragma unroll
        for (int m = 0; m < 4; ++m)
#pragma unroll
            for (int nn = 0; nn < 2; ++nn) {
                half4t p;
#pragma unroll
                for (int r = 0; r < 4; ++r)
                    p[r] = (_Float16)fmaxf(acc[nn][m][r], 0.0f);
                *(half4t*)&h2s[m * 16 + lr][w * 32 + nn * 16 + lq * 4] = p;
            }
    }
    __syncthreads();

    // ---- Layer 3 (MFMA, swapped): wave w -> channels [w*64, w*64+64) ----
    {
        f32x4 acc[4][4];   // [ch-tile][edge-tile]
#pragma unroll
        for (int nn = 0; nn < 4; ++nn) {
            const f32x4 bc = *(const f32x4*)&b3[w * 64 + nn * 16 + lq * 4];
#pragma unroll
            for (int m = 0; m < 4; ++m) acc[nn][m] = bc;
        }
#pragma unroll
        for (int kt = 0; kt < 4; ++kt) {
            half8 wf[4];
#pragma unroll
            for (int nn = 0; nn < 4; ++nn)
                wf[nn] = *(const half8*)(w3h + (w * 64 + nn * 16 + lr) * D2 + kt * 32 + lq * 8);
#pragma unroll
            for (int m = 0; m < 4; ++m) {
                const half8 hf = *(const half8*)&h2s[m * 16 + lr][kt * 32 + lq * 8];
#pragma unroll
                for (int nn = 0; nn < 4; ++nn)
                    acc[nn][m] = __builtin_amdgcn_mfma_f32_16x16x32_f16(wf[nn], hf, acc[nn][m], 0, 0, 0);
            }
        }
        // store: lane -> edge (tile_base+m*16+lr), channels (w*64+nn*16+lq*4 .. +3)
#pragma unroll
        for (int m = 0; m < 4; ++m) {
            const size_t e = tile_base + m * 16 + lr;
#pragma unroll
            for (int nn = 0; nn < 4; ++nn) {
                f32x4 v;
#pragma unroll
                for (int r = 0; r < 4; ++r)
                    v[r] = fmaxf(acc[nn][m][r], 0.0f);
                __builtin_nontemporal_store(v,
                    (f32x4*)(out + e * D3 + w * 64 + nn * 16 + lq * 4));
            }
        }
    }
}

extern "C" void kernel_launch(void* const* d_in, const int* in_sizes, int n_in,
                              void* d_out, int out_size, void* d_ws, size_t ws_size,
                              hipStream_t stream) {
    const float* loc = (const float*)d_in[0];
    const float* W1  = (const float*)d_in[1];
    const float* b1  = (const float*)d_in[2];
    const float* W2  = (const float*)d_in[3];
    const float* b2  = (const float*)d_in[4];
    const float* W3  = (const float*)d_in[5];
    const float* b3  = (const float*)d_in[6];
    float* out = (float*)d_out;

    float* out_ei = out + (size_t)E_TOTAL * D3;     // edge_index region
    _Float16* wsh = (_Float16*)d_ws;                 // f16 weights (80 KB)

    hipLaunchKernelGGL(prepack_kernel, dim3(160), dim3(256), 0, stream, W2, W3, wsh);
    hipLaunchKernelGGL(knn_kernel, dim3(G_NUM, 4), dim3(128), 0, stream, loc, out_ei);
    hipLaunchKernelGGL(mlp_kernel, dim3(E_TOTAL / 64), dim3(256), 0, stream,
                       loc, out_ei, W1, b1, b2, b3, wsh, out);
}